// Round 7
// baseline (1779.042 us; speedup 1.0000x reference)
//
#include <hip/hip_runtime.h>
#include <math.h>

// Problem constants
#define SS 512
#define LL 128
#define WW 64
#define DD 768
#define EG 8192
#define NN 8705          // 1 + S + T
#define MSW 32768        // S*W
#define WSZ 589824       // DD*DD
#define KREL 3840        // 5*DD (feats | pre_agg x4)
#define NPAIR 34820      // 4*NN

typedef __attribute__((ext_vector_type(8))) short bf16x8;
typedef __attribute__((ext_vector_type(4))) float f32x4;

__device__ __forceinline__ ushort f2bf(float f) {
  union { float f; unsigned u; } v; v.f = f;
  unsigned r = (v.u + 0x7FFF + ((v.u >> 16) & 1)) >> 16;
  return (ushort)r;
}
__device__ __forceinline__ float bf2f(ushort b) {
  union { unsigned u; float f; } v; v.u = ((unsigned)b) << 16;
  return v.f;
}
__device__ __forceinline__ void gload16(const void* g, void* l) {
  __builtin_amdgcn_global_load_lds(
      (const __attribute__((address_space(1))) void*)g,
      (__attribute__((address_space(3))) void*)l, 16, 0, 0);
}

// Bijective XCD-aware block swizzle (T1, m204 variant).
__device__ __forceinline__ int2 xcd_swz(int nx) {
  int nwg = nx * (int)gridDim.y;
  int orig = (int)blockIdx.y * nx + (int)blockIdx.x;
  int q = nwg >> 3, r = nwg & 7;
  int xcd = orig & 7, lid = orig >> 3;
  int swz = (xcd < r ? xcd * (q + 1) : r * (q + 1) + (xcd - r) * q) + lid;
  return make_int2(swz / nx, swz % nx);
}

// ---------------------------------------------------------------------------
__global__ __launch_bounds__(256) void k_pos(const float* __restrict__ s_idx,
                                             int* __restrict__ gidx) {
  int row = blockIdx.x * 4 + (threadIdx.x >> 6);
  int lane = threadIdx.x & 63;
  const float* p = s_idx + (size_t)row * LL;
  float v0 = p[lane], v1 = p[lane + 64];
  int idx = v0 > 0.5f ? lane : (v1 > 0.5f ? lane + 64 : -1);
#pragma unroll
  for (int off = 32; off; off >>= 1) {
    int o = __shfl_xor(idx, off, 64);
    idx = o > idx ? o : idx;
  }
  if (lane == 0) {
    int s = row >> 6;
    gidx[row] = s * LL + (idx < 0 ? 0 : idx);
  }
}

// weight transpose/convert: src fp32 [768][768] -> dst bf16 [N][K-stride]
struct WTJob { const float* src; ushort* dst; long stride; };
struct WTJobs { WTJob j[18]; };
__global__ __launch_bounds__(256) void k_wtall(WTJobs wj) {
  __shared__ float t[32][33];
  int w = blockIdx.x / 576, b = blockIdx.x % 576;
  const float* src = wj.j[w].src;
  ushort* dst = wj.j[w].dst;
  long stride = wj.j[w].stride;
  int bx = b % 24, by = b / 24;
  int r0 = by * 32, c0 = bx * 32;
  int lx = threadIdx.x & 31, ly = threadIdx.x >> 5;
#pragma unroll
  for (int i = 0; i < 4; ++i)
    t[ly + i * 8][lx] = src[(size_t)(r0 + ly + i * 8) * DD + c0 + lx];
  __syncthreads();
#pragma unroll
  for (int i = 0; i < 4; ++i)
    dst[(size_t)(c0 + ly + i * 8) * stride + r0 + lx] = f2bf(t[lx][ly + i * 8]);
}

// gather word embeddings -> bf16 [MSW,768]
__global__ __launch_bounds__(256) void k_gather(const float* __restrict__ SE,
                                                const int* __restrict__ gidx,
                                                ushort* __restrict__ WE) {
  size_t i = (size_t)blockIdx.x * 256 + threadIdx.x;
  size_t row = i / 192, q = i % 192;
  float4 v = ((const float4*)(SE + (size_t)gidx[row] * DD))[q];
  ushort4 o;
  o.x = f2bf(v.x); o.y = f2bf(v.y); o.z = f2bf(v.z); o.w = f2bf(v.w);
  ((ushort4*)WE)[i] = o;
}

// ---------------------------------------------------------------------------
// CSR-by-destination build
__global__ __launch_bounds__(256) void k_deg4(const int* __restrict__ dstAll,
                                              int* __restrict__ degc) {
  int i = blockIdx.x * 256 + threadIdx.x;  // 0..4*EG
  int rel = i >> 13;
  atomicAdd(&degc[rel * NN + dstAll[i]], 1);
}
__global__ __launch_bounds__(256) void k_rcp(const int* __restrict__ degc,
                                             float* __restrict__ rdeg) {
  int i = blockIdx.x * 256 + threadIdx.x;
  if (i < NPAIR) rdeg[i] = 1.f / fmaxf((float)degc[i], 1.f);
}
__global__ __launch_bounds__(1024) void k_scan(const int* __restrict__ cnt,
                                               int* __restrict__ offs) {
  __shared__ int part[1024];
  const int tid = threadIdx.x;
  const int C = (NPAIR + 1023) / 1024;  // 35
  int base = tid * C;
  int s = 0;
  for (int j = 0; j < C; ++j) {
    int idx = base + j;
    if (idx < NPAIR) s += cnt[idx];
  }
  part[tid] = s;
  __syncthreads();
  for (int off = 1; off < 1024; off <<= 1) {
    int v = 0;
    if (tid >= off) v = part[tid - off];
    __syncthreads();
    if (tid >= off) part[tid] += v;
    __syncthreads();
  }
  int run = tid ? part[tid - 1] : 0;
  for (int j = 0; j < C; ++j) {
    int idx = base + j;
    if (idx < NPAIR) { offs[idx] = run; run += cnt[idx]; }
  }
  if (tid == 1023) offs[NPAIR] = part[1023];
}
__global__ __launch_bounds__(256) void k_fill(const int* __restrict__ srcAll,
                                              const int* __restrict__ dstAll,
                                              const int* __restrict__ offs,
                                              int* __restrict__ cur,
                                              int* __restrict__ elist) {
  int i = blockIdx.x * 256 + threadIdx.x;  // 0..4*EG
  int rel = i >> 13;
  int id = rel * NN + dstAll[i];
  int pos = offs[id] + atomicAdd(&cur[id], 1);
  elist[pos] = srcAll[i];
}

// pre-aggregation: one wave per (rel,node)
__global__ __launch_bounds__(256) void k_preagg(ushort* __restrict__ FB,
                                                const int* __restrict__ offs,
                                                const int* __restrict__ elist,
                                                const float* __restrict__ rdeg) {
  int id = blockIdx.x * 4 + (threadIdx.x >> 6);
  if (id >= NPAIR) return;
  const int lane = threadIdx.x & 63;
  int rel = id / NN, node = id - rel * NN;
  int beg = offs[id], end = offs[id + 1];
  float acc[12] = {};
  for (int e = beg; e < end; ++e) {
    int src = elist[e];
    const ushort4* p = (const ushort4*)(FB + (size_t)src * KREL);
#pragma unroll
    for (int ps = 0; ps < 3; ++ps) {
      ushort4 u = p[ps * 64 + lane];
      acc[ps * 4 + 0] += bf2f(u.x);
      acc[ps * 4 + 1] += bf2f(u.y);
      acc[ps * 4 + 2] += bf2f(u.z);
      acc[ps * 4 + 3] += bf2f(u.w);
    }
  }
  float rd = rdeg[id];
  ushort4* q = (ushort4*)(FB + (size_t)node * KREL + (size_t)(1 + rel) * DD);
#pragma unroll
  for (int ps = 0; ps < 3; ++ps) {
    ushort4 o;
    o.x = f2bf(acc[ps * 4 + 0] * rd);
    o.y = f2bf(acc[ps * 4 + 1] * rd);
    o.z = f2bf(acc[ps * 4 + 2] * rd);
    o.w = f2bf(acc[ps * 4 + 3] * rd);
    q[ps * 64 + lane] = o;
  }
}

// ---------------------------------------------------------------------------
// bf16 MFMA GEMM body with prefetched double-buffered LDS staging (2-phase):
// stage(kt+1) issued BEFORE compute(kt); single __syncthreads per K-step.
__device__ __forceinline__ void mgemm_body(
    const ushort* __restrict__ A, const ushort* __restrict__ BT,
    const float* __restrict__ bias, const ushort* __restrict__ addCb,
    ushort* __restrict__ Cb, int M, int Kd, int Cstride, int relu,
    int bm, int bn, ushort* As, ushort* Bs) {
  const int tid = threadIdx.x;
  const int wave = tid >> 6, lane = tid & 63;
  const int lrow = lane & 15, quad = lane >> 4;

  const ushort* gA[4];
  const ushort* gB[4];
#pragma unroll
  for (int j = 0; j < 4; ++j) {
    int c = (wave * 4 + j) * 64 + lane;
    int row = c >> 3, kslot = c & 7;
    int kb = kslot ^ (row & 7);
    int ar = bm + row; ar = ar < M ? ar : M - 1;
    gA[j] = A + (size_t)ar * Kd + kb * 8;
    gB[j] = BT + (size_t)(bn + row) * Kd + kb * 8;
  }

  f32x4 acc[4][4];
#pragma unroll
  for (int i = 0; i < 4; ++i)
#pragma unroll
    for (int j = 0; j < 4; ++j) acc[i][j] = (f32x4){0.f, 0.f, 0.f, 0.f};

  const int wm = (wave >> 1) * 64, wn = (wave & 1) * 64;
  const int KT = Kd >> 6;

  // prologue: stage kt=0 into half 0
#pragma unroll
  for (int j = 0; j < 4; ++j) {
    gload16(gA[j], &As[(wave * 4 + j) * 512]);
    gload16(gB[j], &Bs[(wave * 4 + j) * 512]);
    gA[j] += 64;
    gB[j] += 64;
  }
  __syncthreads();

  int cur = 0;
  for (int kt = 0; kt < KT; ++kt) {
    int nxt = cur ^ 1;
    if (kt + 1 < KT) {
#pragma unroll
      for (int j = 0; j < 4; ++j) {
        gload16(gA[j], &As[nxt * 8192 + (wave * 4 + j) * 512]);
        gload16(gB[j], &Bs[nxt * 8192 + (wave * 4 + j) * 512]);
        gA[j] += 64;
        gB[j] += 64;
      }
    }
    const ushort* Asc = As + cur * 8192;
    const ushort* Bsc = Bs + cur * 8192;
#pragma unroll
    for (int ks = 0; ks < 2; ++ks) {
      bf16x8 af[4], bfr[4];
#pragma unroll
      for (int mi = 0; mi < 4; ++mi) {
        int r = wm + mi * 16 + lrow;
        int kc = ks * 4 + quad;
        af[mi] = *(const bf16x8*)&Asc[r * 64 + ((kc ^ (r & 7)) * 8)];
      }
#pragma unroll
      for (int ni = 0; ni < 4; ++ni) {
        int r = wn + ni * 16 + lrow;
        int kc = ks * 4 + quad;
        bfr[ni] = *(const bf16x8*)&Bsc[r * 64 + ((kc ^ (r & 7)) * 8)];
      }
#pragma unroll
      for (int mi = 0; mi < 4; ++mi)
#pragma unroll
        for (int ni = 0; ni < 4; ++ni)
          acc[mi][ni] = __builtin_amdgcn_mfma_f32_16x16x32_bf16(
              af[mi], bfr[ni], acc[mi][ni], 0, 0, 0);
    }
    __syncthreads();
    cur = nxt;
  }

#pragma unroll
  for (int mi = 0; mi < 4; ++mi) {
#pragma unroll
    for (int ni = 0; ni < 4; ++ni) {
      f32x4 v = acc[mi][ni];
      int col = bn + wn + ni * 16 + lrow;
      float bv = bias ? bias[col] : 0.f;
#pragma unroll
      for (int r = 0; r < 4; ++r) {
        int grow = bm + wm + mi * 16 + quad * 4 + r;
        if (grow >= M) continue;
        size_t off = (size_t)grow * Cstride + col;
        float t = v[r] + bv;
        if (addCb) t += bf2f(addCb[off]);
        if (relu) t = fmaxf(t, 0.f);
        Cb[off] = f2bf(t);
      }
    }
  }
}

__global__ __launch_bounds__(256) void k_mgemm(
    const ushort* __restrict__ A, const ushort* __restrict__ BT,
    const float* __restrict__ bias, const ushort* __restrict__ addCb,
    ushort* __restrict__ Cb, int M, int Kd, int Cstride, int relu) {
  __shared__ ushort As[16384], Bs[16384];
  int2 b = xcd_swz(gridDim.x);
  mgemm_body(A, BT, bias, addCb, Cb, M, Kd, Cstride, relu,
             b.x * 128, b.y * 128, As, Bs);
}

// fused Q,K projection: grid (12, 256); x<6 -> Q, x>=6 -> K
__global__ __launch_bounds__(256) void k_mgemm_qk(
    const ushort* __restrict__ A, const ushort* __restrict__ BTq,
    const ushort* __restrict__ BTk, const float* __restrict__ bq,
    const float* __restrict__ bk, ushort* __restrict__ Qb,
    ushort* __restrict__ Kb) {
  __shared__ ushort As[16384], Bs[16384];
  int2 b = xcd_swz(gridDim.x);
  int sel = b.y >= 6;
  mgemm_body(A, sel ? BTk : BTq, sel ? bk : bq, nullptr,
             sel ? Kb : Qb, MSW, DD, DD, 0,
             b.x * 128, (b.y - sel * 6) * 128, As, Bs);
}

// Second gated-GCN GEMM with fused gate epilogue:
// computes L2 = Ol @ W2; then G = L2 + b2 + G1 (= Od@W1 + b1, bf16);
// g = sigmoid(G); dst = relu(g*Od + (1-g)*Ol + gb) [+ SE residual].
// K=768 (12 steps), grid (6, 256) — wide, short serial chain.
__global__ __launch_bounds__(256) void k_mgemm_gate2(
    const ushort* __restrict__ Aol, const ushort* __restrict__ BT,
    const float* __restrict__ b2, const ushort* __restrict__ G1,
    const ushort* __restrict__ Od, const float* __restrict__ gb,
    const float* __restrict__ SE, const int* __restrict__ gidx, int fuse_res,
    ushort* __restrict__ dst) {
  __shared__ ushort As[16384], Bs[16384];
  const int tid = threadIdx.x;
  const int wave = tid >> 6, lane = tid & 63;
  const int lrow = lane & 15, quad = lane >> 4;
  int2 bxy = xcd_swz(gridDim.x);
  const int bm = bxy.x * 128, bn = bxy.y * 128;

  const ushort* gA[4];
  const ushort* gB[4];
#pragma unroll
  for (int j = 0; j < 4; ++j) {
    int c = (wave * 4 + j) * 64 + lane;
    int row = c >> 3, kslot = c & 7;
    int kb = kslot ^ (row & 7);
    gA[j] = Aol + (size_t)(bm + row) * DD + kb * 8;
    gB[j] = BT + (size_t)(bn + row) * DD + kb * 8;
  }

  f32x4 acc[4][4];
#pragma unroll
  for (int i = 0; i < 4; ++i)
#pragma unroll
    for (int j = 0; j < 4; ++j) acc[i][j] = (f32x4){0.f, 0.f, 0.f, 0.f};

  const int wm = (wave >> 1) * 64, wn = (wave & 1) * 64;

  // prologue
#pragma unroll
  for (int j = 0; j < 4; ++j) {
    gload16(gA[j], &As[(wave * 4 + j) * 512]);
    gload16(gB[j], &Bs[(wave * 4 + j) * 512]);
    gA[j] += 64;
    gB[j] += 64;
  }
  __syncthreads();

  int cur = 0;
  for (int kt = 0; kt < 12; ++kt) {
    int nxt = cur ^ 1;
    if (kt + 1 < 12) {
#pragma unroll
      for (int j = 0; j < 4; ++j) {
        gload16(gA[j], &As[nxt * 8192 + (wave * 4 + j) * 512]);
        gload16(gB[j], &Bs[nxt * 8192 + (wave * 4 + j) * 512]);
        gA[j] += 64;
        gB[j] += 64;
      }
    }
    const ushort* Asc = As + cur * 8192;
    const ushort* Bsc = Bs + cur * 8192;
#pragma unroll
    for (int ks = 0; ks < 2; ++ks) {
      bf16x8 af[4], bfr[4];
#pragma unroll
      for (int mi = 0; mi < 4; ++mi) {
        int r = wm + mi * 16 + lrow;
        int kc = ks * 4 + quad;
        af[mi] = *(const bf16x8*)&Asc[r * 64 + ((kc ^ (r & 7)) * 8)];
      }
#pragma unroll
      for (int ni = 0; ni < 4; ++ni) {
        int r = wn + ni * 16 + lrow;
        int kc = ks * 4 + quad;
        bfr[ni] = *(const bf16x8*)&Bsc[r * 64 + ((kc ^ (r & 7)) * 8)];
      }
#pragma unroll
      for (int mi = 0; mi < 4; ++mi)
#pragma unroll
        for (int ni = 0; ni < 4; ++ni)
          acc[mi][ni] = __builtin_amdgcn_mfma_f32_16x16x32_bf16(
              af[mi], bfr[ni], acc[mi][ni], 0, 0, 0);
    }
    __syncthreads();
    cur = nxt;
  }

#pragma unroll
  for (int mi = 0; mi < 4; ++mi) {
#pragma unroll
    for (int ni = 0; ni < 4; ++ni) {
      f32x4 v = acc[mi][ni];
      int col = bn + wn + ni * 16 + lrow;
      float bv = b2[col];
      float gbv = gb[col];
#pragma unroll
      for (int r = 0; r < 4; ++r) {
        int grow = bm + wm + mi * 16 + quad * 4 + r;
        size_t off = (size_t)grow * DD + col;
        float G = v[r] + bv + bf2f(G1[off]);
        float g = 1.f / (1.f + __expf(-G));
        float od = bf2f(Od[off]), ol = bf2f(Aol[off]);
        float t = fmaxf(g * od + (1.f - g) * ol + gbv, 0.f);
        if (fuse_res) t += SE[(size_t)gidx[grow] * DD + col];
        dst[off] = f2bf(t);
      }
    }
  }
}

// ---------------------------------------------------------------------------
// Attention (MFMA QK^T) + exact entmax-1.5 in native MFMA fragment layout.
__device__ __forceinline__ void xlev4(float z[4], int j, bool ma, bool mb,
                                      bool mc, bool md) {
  float o0 = __shfl_xor(z[0], j, 16);
  float o1 = __shfl_xor(z[1], j, 16);
  float o2 = __shfl_xor(z[2], j, 16);
  float o3 = __shfl_xor(z[3], j, 16);
  z[0] = ma ? fmaxf(z[0], o0) : fminf(z[0], o0);
  z[1] = mb ? fmaxf(z[1], o1) : fminf(z[1], o1);
  z[2] = mc ? fmaxf(z[2], o2) : fminf(z[2], o2);
  z[3] = md ? fmaxf(z[3], o3) : fminf(z[3], o3);
}
__device__ __forceinline__ void rpair(float z[4], int a, int b, bool maxToA) {
  float hi = fmaxf(z[a], z[b]), lo = fminf(z[a], z[b]);
  z[a] = maxToA ? hi : lo;
  z[b] = maxToA ? lo : hi;
}

__global__ __launch_bounds__(256) void k_attn(const ushort* __restrict__ Q,
                                              const ushort* __restrict__ K,
                                              float* __restrict__ part) {
  __shared__ __align__(16) ushort ks[2][6144];
  const int s = blockIdx.x, hp = blockIdx.y;
  const int tid = threadIdx.x;
  const int wv = tid >> 6, lane = tid & 63;
  const int lrow = lane & 15, quad = lane >> 4;
  const int m0 = wv * 16;
  const float SC2 = 0.05103103630798288f;  // 0.5 / sqrt(96)
  const int h0 = hp * 2, h1 = hp * 2 + 1;

  const bool b1 = (lrow & 1) == 0, b2 = (lrow & 2) == 0,
             b4 = (lrow & 4) == 0, b8 = (lrow & 8) == 0;
  const bool s21 = b2 ? b1 : !b1;
  const bool s42 = b4 ? b2 : !b2, s41 = b4 ? b1 : !b1;
  const bool s84 = b8 ? b4 : !b4, s82 = b8 ? b2 : !b2, s81 = b8 ? b1 : !b1;

  float regacc[16];
#pragma unroll
  for (int i = 0; i < 16; ++i) regacc[i] = 0.f;

#pragma unroll
  for (int j = 0; j < 3; ++j) {
    int c = (j * 4 + wv) * 64 + lane;
    int row = c / 12, o = c - row * 12;
    gload16(K + (size_t)(s * 64 + row) * DD + h0 * 96 + o * 8,
            &ks[0][(j * 4 + wv) * 512]);
  }
  const ushort* qb0 = Q + (size_t)(s * 64 + m0 + lrow) * DD + h0 * 96 + quad * 8;
  bf16x8 qa0 = *(const bf16x8*)(qb0);
  bf16x8 qa1 = *(const bf16x8*)(qb0 + 32);
  bf16x8 qa2 = *(const bf16x8*)(qb0 + 64);
  __syncthreads();

#pragma unroll
  for (int hh = 0; hh < 2; ++hh) {
    f32x4 acc4[4];
#pragma unroll
    for (int t = 0; t < 4; ++t) acc4[t] = (f32x4){0.f, 0.f, 0.f, 0.f};
#pragma unroll
    for (int k = 0; k < 3; ++k) {
      bf16x8 a = (k == 0) ? qa0 : (k == 1) ? qa1 : qa2;
#pragma unroll
      for (int t = 0; t < 4; ++t) {
        bf16x8 b =
            *(const bf16x8*)&ks[hh][(t * 16 + lrow) * 96 + k * 32 + quad * 8];
        acc4[t] = __builtin_amdgcn_mfma_f32_16x16x32_bf16(a, b, acc4[t], 0, 0, 0);
      }
    }
    if (hh == 0) {
#pragma unroll
      for (int j = 0; j < 3; ++j) {
        int c = (j * 4 + wv) * 64 + lane;
        int row = c / 12, o = c - row * 12;
        gload16(K + (size_t)(s * 64 + row) * DD + h1 * 96 + o * 8,
                &ks[1][(j * 4 + wv) * 512]);
      }
      const ushort* qb1 =
          Q + (size_t)(s * 64 + m0 + lrow) * DD + h1 * 96 + quad * 8;
      qa0 = *(const bf16x8*)(qb1);
      qa1 = *(const bf16x8*)(qb1 + 32);
      qa2 = *(const bf16x8*)(qb1 + 64);
    }

#pragma unroll
    for (int r = 0; r < 4; ++r) {
      float z[4];
#pragma unroll
      for (int t = 0; t < 4; ++t) z[t] = acc4[t][r] * SC2;
      xlev4(z, 1, s21, s21, s21, s21);                      // k=2
      xlev4(z, 2, s42, s42, s42, s42);                      // k=4
      xlev4(z, 1, s41, s41, s41, s41);
      xlev4(z, 4, s84, s84, s84, s84);                      // k=8
      xlev4(z, 2, s82, s82, s82, s82);
      xlev4(z, 1, s81, s81, s81, s81);
      xlev4(z, 8, b8, !b8, b8, !b8);                        // k=16
      xlev4(z, 4, b4, !b4, b4, !b4);
      xlev4(z, 2, b2, !b2, b2, !b2);
      xlev4(z, 1, b1, !b1, b1, !b1);
      rpair(z, 0, 1, true); rpair(z, 2, 3, false);          // k=32, j=16
      xlev4(z, 8, b8, b8, !b8, !b8);
      xlev4(z, 4, b4, b4, !b4, !b4);
      xlev4(z, 2, b2, b2, !b2, !b2);
      xlev4(z, 1, b1, b1, !b1, !b1);
      rpair(z, 0, 2, true); rpair(z, 1, 3, true);           // k=64, j=32
      rpair(z, 0, 1, true); rpair(z, 2, 3, true);           // k=64, j=16
      xlev4(z, 8, b8, b8, b8, b8);
      xlev4(z, 4, b4, b4, b4, b4);
      xlev4(z, 2, b2, b2, b2, b2);
      xlev4(z, 1, b1, b1, b1, b1);

      float zmax = __shfl(z[0], 0, 16);
      float cz[4], czz[4];
#pragma unroll
      for (int t = 0; t < 4; ++t) {
        z[t] -= zmax;
        cz[t] = z[t];
        czz[t] = z[t] * z[t];
      }
#pragma unroll
      for (int off = 1; off < 16; off <<= 1) {
#pragma unroll
        for (int t = 0; t < 4; ++t) {
          float ta = __shfl_up(cz[t], off, 16);
          float tb = __shfl_up(czz[t], off, 16);
          if (lrow >= off) { cz[t] += ta; czz[t] += tb; }
        }
      }
      float accz = 0.f, acczz = 0.f;
      float tau[4];
      int cnt = 0;
#pragma unroll
      for (int t = 0; t < 4; ++t) {
        float tz = __shfl(cz[t], 15, 16);
        float tzz = __shfl(czz[t], 15, 16);
        cz[t] += accz; czz[t] += acczz;
        accz += tz; acczz += tzz;
        float kk = (float)(t * 16 + lrow + 1);
        float mean = cz[t] / kk;
        float ssv = kk * (czz[t] / kk - mean * mean);
        float delta = (1.f - ssv) / kk;
        float sq = delta > 0.f ? sqrtf(delta) : 0.f;
        tau[t] = mean - sq;
        cnt += (tau[t] <= z[t]) ? 1 : 0;
      }
#pragma unroll
      for (int off = 1; off < 16; off <<= 1) cnt += __shfl_xor(cnt, off, 16);
      int ts = (cnt - 1) >> 4, ls = (cnt - 1) & 15;
      float tt = ts == 0 ? tau[0] : ts == 1 ? tau[1] : ts == 2 ? tau[2] : tau[3];
      float tau_star = __shfl(tt, ls, 16);
#pragma unroll
      for (int t = 0; t < 4; ++t) {
        float p = fmaxf(acc4[t][r] * SC2 - zmax - tau_star, 0.f);
        regacc[r * 4 + t] += p * p;
      }
    }
    if (hh == 0) __syncthreads();
  }

#pragma unroll
  for (int r = 0; r < 4; ++r)
#pragma unroll
    for (int t = 0; t < 4; ++t)
      part[(size_t)hp * 2097152 +
           ((size_t)s * 64 + m0 + quad * 4 + r) * 64 + t * 16 + lrow] =
          regacc[r * 4 + t] * 0.125f;
}

// reduce 4 head-pair partials -> bf16 latent adjacency
__global__ __launch_bounds__(256) void k_latred(const float* __restrict__ part,
                                                ushort* __restrict__ latbf) {
  size_t i = (size_t)blockIdx.x * 256 + threadIdx.x;  // float4 units, 524288
  float4 a = ((const float4*)part)[i];
  float4 b = ((const float4*)(part + 2097152))[i];
  float4 c = ((const float4*)(part + 4194304))[i];
  float4 d = ((const float4*)(part + 6291456))[i];
  ushort4 o;
  o.x = f2bf(a.x + b.x + c.x + d.x);
  o.y = f2bf(a.y + b.y + c.y + d.y);
  o.z = f2bf(a.z + b.z + c.z + d.z);
  o.w = f2bf(a.w + b.w + c.w + d.w);
  ((ushort4*)latbf)[i] = o;
}

// ---------------------------------------------------------------------------
// Od[s]=dep[s]@Hh[s], Ol[s]=lat[s]@Hh[s]; 128-col tiles, grid (6, SS)
__global__ __launch_bounds__(256) void k_dualadj(const float* __restrict__ dep,
                                                 const ushort* __restrict__ lat,
                                                 const ushort* __restrict__ Hh,
                                                 ushort* __restrict__ Od,
                                                 ushort* __restrict__ Ol) {
  __shared__ float Pd[64][68];
  __shared__ ushort Pl[64][68];
  __shared__ float Hc[64][132];
  int2 bxy = xcd_swz(gridDim.x);
  const int s = bxy.x;
  const int c0 = bxy.y * 128;
  const int tid = threadIdx.x;
  const int tx = tid & 15, ty = tid >> 4;
  for (int i = tid; i < 4096; i += 256)
    Pd[i >> 6][i & 63] = dep[(size_t)s * 4096 + i];
  for (int i = tid; i < 1024; i += 256) {
    int r = i >> 4, c = (i & 15) * 4;
    ushort4 u = ((const ushort4*)(lat + (size_t)s * 4096))[i];
    Pl[r][c + 0] = u.x; Pl[r][c + 1] = u.y;
    Pl[r][c + 2] = u.z; Pl[r][c + 3] = u.w;
  }
  for (int i = tid; i < 2048; i += 256) {
    int r = i >> 5, c = (i & 31) * 4;
    ushort4 u = *(const ushort4*)(Hh + (size_t)(s * 64 + r) * DD + c0 + c);
    float4 f;
    f.x = bf2f(u.x); f.y = bf2f(u.y); f.z = bf2f(u.z); f.w = bf2f(u.w);
    *(float4*)&Hc[r][c] = f;
  }
  __syncthreads();
  float ad[4][8] = {}, al[4][8] = {};
  for (int w2 = 0; w2 < 64; ++w2) {
    float4 b0 = *(const float4*)&Hc[w2][tx * 4];
    float4 b1 = *(const float4*)&Hc[w2][64 + tx * 4];
    float bb[8] = {b0.x, b0.y, b0.z, b0.w, b1.x, b1.y, b1.z, b1.w};
    float pd[4], pl[4];
#pragma unroll
    for (int i = 0; i < 4; ++i) {
      pd[i] = Pd[ty * 4 + i][w2];
      pl[i] = bf2f(Pl[ty * 4 + i][w2]);
    }
#pragma unroll
    for (int i = 0; i < 4; ++i)
#pragma unroll
      for (int j = 0; j < 8; ++j) {
        ad[i][j] = fmaf(pd[i], bb[j], ad[i][j]);
        al[i][j] = fmaf(pl[i], bb[j], al[i][j]);
      }
  }
#pragma unroll
  for (int i = 0; i < 4; ++i) {
    size_t ro = (size_t)(s * 64 + ty * 4 + i) * DD + c0;
    ushort4 v;
#pragma unroll
    for (int hh = 0; hh < 2; ++hh) {
      v.x = f2bf(ad[i][hh * 4 + 0]); v.y = f2bf(ad[i][hh * 4 + 1]);
      v.z = f2bf(ad[i][hh * 4 + 2]); v.w = f2bf(ad[i][hh * 4 + 3]);
      *(ushort4*)&Od[ro + hh * 64 + tx * 4] = v;
      v.x = f2bf(al[i][hh * 4 + 0]); v.y = f2bf(al[i][hh * 4 + 1]);
      v.z = f2bf(al[i][hh * 4 + 2]); v.w = f2bf(al[i][hh * 4 + 3]);
      *(ushort4*)&Ol[ro + hh * 64 + tx * 4] = v;
    }
  }
}

// node feature assembly -> bf16 FBIG[NN, KREL] (cols 0:768)
__global__ __launch_bounds__(256) void k_feats(const float* __restrict__ doc,
                                               const float* __restrict__ scls,
                                               const int* __restrict__ t_sid,
                                               const int* __restrict__ t_index,
                                               const ushort* __restrict__ X,
                                               ushort* __restrict__ F) {
  size_t i = (size_t)blockIdx.x * 256 + threadIdx.x;
  if (i >= (size_t)NN * 192) return;
  size_t n = i / 192, q = i % 192;
  ushort4 o;
  if (n <= SS) {
    float4 v = (n == 0) ? ((const float4*)doc)[q]
                        : ((const float4*)scls)[(n - 1) * 192 + q];
    o.x = f2bf(v.x); o.y = f2bf(v.y); o.z = f2bf(v.z); o.w = f2bf(v.w);
  } else {
    size_t t = n - 1 - SS;
    size_t row = (size_t)t_sid[t] * WW + t_index[t];
    o = ((const ushort4*)X)[row * 192 + q];
  }
  ((ushort4*)(F + n * KREL))[q] = o;
}

// final predictor; F/h1 strided (FBIG col 0), h2 contiguous
__global__ __launch_bounds__(256) void k_pred(const ushort* __restrict__ F,
                                              const ushort* __restrict__ h1,
                                              const ushort* __restrict__ h2,
                                              const float* __restrict__ pw,
                                              const float* __restrict__ pb,
                                              float* __restrict__ out) {
  const int n = blockIdx.x;
  const int tid = threadIdx.x;
  float acc[5] = {};
  for (int k = tid; k < 3 * DD; k += 256) {
    float v;
    if (k < DD) v = bf2f(F[(size_t)n * KREL + k]);
    else if (k < 2 * DD) v = bf2f(h1[(size_t)n * KREL + k - DD]);
    else v = bf2f(h2[(size_t)n * DD + k - 2 * DD]);
    const float* w = pw + (size_t)k * 5;
#pragma unroll
    for (int o = 0; o < 5; ++o) acc[o] = fmaf(v, w[o], acc[o]);
  }
#pragma unroll
  for (int o = 0; o < 5; ++o)
    for (int off = 32; off; off >>= 1) acc[o] += __shfl_xor(acc[o], off, 64);
  __shared__ float red[5][4];
  const int wv = tid >> 6, lane = tid & 63;
  if (lane == 0)
#pragma unroll
    for (int o = 0; o < 5; ++o) red[o][wv] = acc[o];
  __syncthreads();
  if (tid == 0)
#pragma unroll
    for (int o = 0; o < 5; ++o)
      out[(size_t)n * 5 + o] = red[o][0] + red[o][1] + red[o][2] + red[o][3] + pb[o];
}

// ---------------------------------------------------------------------------
extern "C" void kernel_launch(void* const* d_in, const int* in_sizes, int n_in,
                              void* d_out, int out_size, void* d_ws, size_t ws_size,
                              hipStream_t stream) {
  const float* sent_embed = (const float*)d_in[0];
  const float* s_idx      = (const float*)d_in[1];
  const float* dep_adj    = (const float*)d_in[2];
  const float* doc_cls    = (const float*)d_in[3];
  const float* sent_cls   = (const float*)d_in[4];
  const int*   t_sid      = (const int*)d_in[5];
  const int*   t_index    = (const int*)d_in[6];
  const int*   e_src      = (const int*)d_in[7];
  const int*   e_dst      = (const int*)d_in[8];
  const float* wq_b = (const float*)d_in[10];
  const float* wk_b = (const float*)d_in[12];
  const float* gc1_b   = (const float*)d_in[14];
  const float* gc1_l1b = (const float*)d_in[16];
  const float* gc1_l2b = (const float*)d_in[18];
  const float* gc2_b   = (const float*)d_in[20];
  const float* gc2_l1b = (const float*)d_in[22];
  const float* gc2_l2b = (const float*)d_in[24];
  const float* rel1_b = (const float*)d_in[27];
  const float* rel2_b = (const float*)d_in[30];
  const float* pred_w = (const float*)d_in[31];
  const float* pred_b = (const float*)d_in[32];
  float* out = (float*)d_out;

  // workspace carve (byte offsets), ~264 MiB total
  char* W = (char*)d_ws;
  ushort* A0 = (ushort*)W;                          // 64 MiB: WEbf -> FBIG2
  ushort* A1 = (ushort*)(W + (64ll << 20));         // 64 MiB: Q/Hh/G1 -> FBIG1
  ushort* A2 = (ushort*)(W + (128ll << 20));        // 48 MiB: K/Od
  ushort* A3 = (ushort*)(W + (176ll << 20));        // 48 MiB: PART/Ol
  ushort* LATbf = (ushort*)(W + (224ll << 20));     // 4 MiB
  ushort* WBF = (ushort*)(W + (228ll << 20));       // 9 MiB (8 matrices)
  ushort* WR  = (ushort*)(W + (238ll << 20));       // 11.25 MiB (2x768x3840)
  ushort* H2  = (ushort*)(W + (250ll << 20));       // 12.75 MiB
  char* M0 = W + (263ll << 20);
  int*   GIDX = (int*)M0;                           // 131072 B
  int*   DEGC = (int*)(M0 + 140000);
  float* RDEG = (float*)(M0 + 280000);
  int*   OFFS = (int*)(M0 + 420000);                // (NPAIR+1)*4
  int*   CUR  = (int*)(M0 + 560000);
  int*   ELIST= (int*)(M0 + 700000);                // 131072 B

  ushort* WEbf = A0;
  ushort* Qbf = A1, *Kbf = A2;
  float*  PART = (float*)A3;
  ushort* Hh = A1, *Od = A2, *Ol = A3, *G1 = A1;
  ushort* FBIG1 = A1;
  ushort* FBIG2 = A0;
  const size_t WRSZ = (size_t)DD * KREL;  // 2949120

  WTJobs wj;
  wj.j[0] = {(const float*)d_in[9],  WBF + 0 * (size_t)WSZ, DD};   // wq
  wj.j[1] = {(const float*)d_in[11], WBF + 1 * (size_t)WSZ, DD};   // wk
  wj.j[2] = {(const float*)d_in[13], WBF + 2 * (size_t)WSZ, DD};   // gc1_w
  wj.j[3] = {(const float*)d_in[15], WBF + 3 * (size_t)WSZ, DD};   // gc1_l1w
  wj.j[4] = {(const float*)d_in[17], WBF + 4 * (size_t)WSZ, DD};   // gc1_l2w
  wj.j[5] = {(const float*)d_in[19], WBF + 5 * (size_t)WSZ, DD};   // gc2_w
  wj.j[6] = {(const float*)d_in[21], WBF + 6 * (size_t)WSZ, DD};   // gc2_l1w
  wj.j[7] = {(const float*)d_in[23], WBF + 7 * (size_t)WSZ, DD};   // gc2_l2w
  wj.j[8] = {(const float*)d_in[26], WR + 0 * WRSZ, KREL};         // rel1 loop
  for (int r = 0; r < 4; ++r)
    wj.j[9 + r] = {(const float*)d_in[25] + (size_t)r * WSZ,
                   WR + 0 * WRSZ + (size_t)(1 + r) * DD, KREL};
  wj.j[13] = {(const float*)d_in[29], WR + 1 * WRSZ, KREL};        // rel2 loop
  for (int r = 0; r < 4; ++r)
    wj.j[14 + r] = {(const float*)d_in[28] + (size_t)r * WSZ,
                    WR + 1 * WRSZ + (size_t)(1 + r) * DD, KREL};

  dim3 blk(256);

  // 0) prep
  k_wtall<<<18 * 576, blk, 0, stream>>>(wj);
  k_pos<<<MSW / 4, blk, 0, stream>>>(s_idx, GIDX);
  k_gather<<<24576, blk, 0, stream>>>(sent_embed, GIDX, WEbf);
  hipMemsetAsync(DEGC, 0, NPAIR * 4, stream);
  hipMemsetAsync(CUR, 0, NPAIR * 4, stream);
  k_deg4<<<4 * EG / 256, blk, 0, stream>>>(e_dst, DEGC);
  k_rcp<<<(NPAIR + 255) / 256, blk, 0, stream>>>(DEGC, RDEG);
  k_scan<<<1, 1024, 0, stream>>>(DEGC, OFFS);
  k_fill<<<4 * EG / 256, blk, 0, stream>>>(e_src, e_dst, OFFS, CUR, ELIST);

  // 1) Q,K projections + attention + reduce
  k_mgemm_qk<<<dim3(12, 256), blk, 0, stream>>>(WEbf, WBF + 0 * (size_t)WSZ,
                                                WBF + 1 * (size_t)WSZ, wq_b, wk_b,
                                                Qbf, Kbf);
  k_attn<<<dim3(SS, 4), blk, 0, stream>>>(Qbf, Kbf, PART);
  k_latred<<<2048, blk, 0, stream>>>(PART, LATbf);

  // 2) gated GCN layers: Hh GEMM; dualadj; Od@W1 -> G1; gate2 (Ol@W2 + fuse)
  const float* l1b[2] = {gc1_l1b, gc2_l1b};
  const float* l2b[2] = {gc1_l2b, gc2_l2b};
  const float* gb[2] = {gc1_b, gc2_b};
  for (int l = 0; l < 2; ++l) {
    k_mgemm<<<dim3(6, 256), blk, 0, stream>>>(WEbf,
        WBF + (size_t)(2 + 3 * l) * WSZ, nullptr, nullptr, Hh, MSW, DD, DD, 0);
    k_dualadj<<<dim3(6, SS), blk, 0, stream>>>(dep_adj, LATbf, Hh, Od, Ol);
    k_mgemm<<<dim3(6, 256), blk, 0, stream>>>(Od,
        WBF + (size_t)(3 + 3 * l) * WSZ, l1b[l], nullptr, G1, MSW, DD, DD, 0);
    k_mgemm_gate2<<<dim3(6, 256), blk, 0, stream>>>(
        Ol, WBF + (size_t)(4 + 3 * l) * WSZ, l2b[l], G1, Od, gb[l],
        sent_embed, GIDX, l == 1 ? 1 : 0, WEbf);
  }

  // 3) node features into FBIG1 col 0
  k_feats<<<6529, blk, 0, stream>>>(doc_cls, sent_cls, t_sid, t_index, WEbf, FBIG1);

  // 4) two relational GCN layers: CSR gather + one fused K=3840 GEMM each
  k_preagg<<<(NPAIR + 3) / 4, blk, 0, stream>>>(FBIG1, OFFS, ELIST, RDEG);
  k_mgemm<<<dim3(6, 69), blk, 0, stream>>>(FBIG1, WR + 0 * WRSZ, rel1_b, nullptr,
                                           FBIG2, NN, KREL, KREL, 1);
  k_preagg<<<(NPAIR + 3) / 4, blk, 0, stream>>>(FBIG2, OFFS, ELIST, RDEG);
  k_mgemm<<<dim3(6, 69), blk, 0, stream>>>(FBIG2, WR + 1 * WRSZ, rel2_b, nullptr,
                                           H2, NN, KREL, DD, 1);

  // 5) predictor
  k_pred<<<NN, blk, 0, stream>>>(FBIG1, FBIG2, H2, pred_w, pred_b, out);
}

// Round 9
// 1560.745 us; speedup vs baseline: 1.1399x; 1.1399x over previous
//
#include <hip/hip_runtime.h>
#include <math.h>

// Problem constants
#define SS 512
#define LL 128
#define WW 64
#define DD 768
#define EG 8192
#define NN 8705          // 1 + S + T
#define MSW 32768        // S*W
#define WSZ 589824       // DD*DD
#define KREL 3840        // 5*DD (feats | pre_agg x4)
#define NPAIR 34820      // 4*NN

typedef __attribute__((ext_vector_type(8))) short bf16x8;
typedef __attribute__((ext_vector_type(4))) float f32x4;
typedef __attribute__((ext_vector_type(8))) unsigned short u16x8;

__device__ __forceinline__ ushort f2bf(float f) {
  union { float f; unsigned u; } v; v.f = f;
  unsigned r = (v.u + 0x7FFF + ((v.u >> 16) & 1)) >> 16;
  return (ushort)r;
}
__device__ __forceinline__ float bf2f(ushort b) {
  union { unsigned u; float f; } v; v.u = ((unsigned)b) << 16;
  return v.f;
}
__device__ __forceinline__ void gload16(const void* g, void* l) {
  __builtin_amdgcn_global_load_lds(
      (const __attribute__((address_space(1))) void*)g,
      (__attribute__((address_space(3))) void*)l, 16, 0, 0);
}

// Bijective XCD-aware block swizzle (T1, m204 variant).
__device__ __forceinline__ int2 xcd_swz(int nx) {
  int nwg = nx * (int)gridDim.y;
  int orig = (int)blockIdx.y * nx + (int)blockIdx.x;
  int q = nwg >> 3, r = nwg & 7;
  int xcd = orig & 7, lid = orig >> 3;
  int swz = (xcd < r ? xcd * (q + 1) : r * (q + 1) + (xcd - r) * q) + lid;
  return make_int2(swz / nx, swz % nx);
}

// ---------------------------------------------------------------------------
__global__ __launch_bounds__(256) void k_pos(const float* __restrict__ s_idx,
                                             int* __restrict__ gidx) {
  int row = blockIdx.x * 4 + (threadIdx.x >> 6);
  int lane = threadIdx.x & 63;
  const float* p = s_idx + (size_t)row * LL;
  float v0 = p[lane], v1 = p[lane + 64];
  int idx = v0 > 0.5f ? lane : (v1 > 0.5f ? lane + 64 : -1);
#pragma unroll
  for (int off = 32; off; off >>= 1) {
    int o = __shfl_xor(idx, off, 64);
    idx = o > idx ? o : idx;
  }
  if (lane == 0) {
    int s = row >> 6;
    gidx[row] = s * LL + (idx < 0 ? 0 : idx);
  }
}

// weight transpose/convert: src fp32 [768][768] -> dst bf16 [N][K-stride]
struct WTJob { const float* src; ushort* dst; long stride; };
struct WTJobs { WTJob j[18]; };
__global__ __launch_bounds__(256) void k_wtall(WTJobs wj) {
  __shared__ float t[32][33];
  int w = blockIdx.x / 576, b = blockIdx.x % 576;
  const float* src = wj.j[w].src;
  ushort* dst = wj.j[w].dst;
  long stride = wj.j[w].stride;
  int bx = b % 24, by = b / 24;
  int r0 = by * 32, c0 = bx * 32;
  int lx = threadIdx.x & 31, ly = threadIdx.x >> 5;
#pragma unroll
  for (int i = 0; i < 4; ++i)
    t[ly + i * 8][lx] = src[(size_t)(r0 + ly + i * 8) * DD + c0 + lx];
  __syncthreads();
#pragma unroll
  for (int i = 0; i < 4; ++i)
    dst[(size_t)(c0 + ly + i * 8) * stride + r0 + lx] = f2bf(t[lx][ly + i * 8]);
}

// gather word embeddings -> bf16 [MSW,768]
__global__ __launch_bounds__(256) void k_gather(const float* __restrict__ SE,
                                                const int* __restrict__ gidx,
                                                ushort* __restrict__ WE) {
  size_t i = (size_t)blockIdx.x * 256 + threadIdx.x;
  size_t row = i / 192, q = i % 192;
  float4 v = ((const float4*)(SE + (size_t)gidx[row] * DD))[q];
  ushort4 o;
  o.x = f2bf(v.x); o.y = f2bf(v.y); o.z = f2bf(v.z); o.w = f2bf(v.w);
  ((ushort4*)WE)[i] = o;
}

// ---------------------------------------------------------------------------
// CSR-by-destination build
__global__ __launch_bounds__(256) void k_deg4(const int* __restrict__ dstAll,
                                              int* __restrict__ degc) {
  int i = blockIdx.x * 256 + threadIdx.x;  // 0..4*EG
  int rel = i >> 13;
  atomicAdd(&degc[rel * NN + dstAll[i]], 1);
}
__global__ __launch_bounds__(256) void k_rcp(const int* __restrict__ degc,
                                             float* __restrict__ rdeg) {
  int i = blockIdx.x * 256 + threadIdx.x;
  if (i < NPAIR) rdeg[i] = 1.f / fmaxf((float)degc[i], 1.f);
}
__global__ __launch_bounds__(1024) void k_scan(const int* __restrict__ cnt,
                                               int* __restrict__ offs) {
  __shared__ int part[1024];
  const int tid = threadIdx.x;
  const int C = (NPAIR + 1023) / 1024;  // 35
  int base = tid * C;
  int s = 0;
  for (int j = 0; j < C; ++j) {
    int idx = base + j;
    if (idx < NPAIR) s += cnt[idx];
  }
  part[tid] = s;
  __syncthreads();
  for (int off = 1; off < 1024; off <<= 1) {
    int v = 0;
    if (tid >= off) v = part[tid - off];
    __syncthreads();
    if (tid >= off) part[tid] += v;
    __syncthreads();
  }
  int run = tid ? part[tid - 1] : 0;
  for (int j = 0; j < C; ++j) {
    int idx = base + j;
    if (idx < NPAIR) { offs[idx] = run; run += cnt[idx]; }
  }
  if (tid == 1023) offs[NPAIR] = part[1023];
}
__global__ __launch_bounds__(256) void k_fill(const int* __restrict__ srcAll,
                                              const int* __restrict__ dstAll,
                                              const int* __restrict__ offs,
                                              int* __restrict__ cur,
                                              int* __restrict__ elist) {
  int i = blockIdx.x * 256 + threadIdx.x;  // 0..4*EG
  int rel = i >> 13;
  int id = rel * NN + dstAll[i];
  int pos = offs[id] + atomicAdd(&cur[id], 1);
  elist[pos] = srcAll[i];
}

// pre-aggregation: one wave per (rel,node)
__global__ __launch_bounds__(256) void k_preagg(ushort* __restrict__ FB,
                                                const int* __restrict__ offs,
                                                const int* __restrict__ elist,
                                                const float* __restrict__ rdeg) {
  int id = blockIdx.x * 4 + (threadIdx.x >> 6);
  if (id >= NPAIR) return;
  const int lane = threadIdx.x & 63;
  int rel = id / NN, node = id - rel * NN;
  int beg = offs[id], end = offs[id + 1];
  float acc[12] = {};
  for (int e = beg; e < end; ++e) {
    int src = elist[e];
    const ushort4* p = (const ushort4*)(FB + (size_t)src * KREL);
#pragma unroll
    for (int ps = 0; ps < 3; ++ps) {
      ushort4 u = p[ps * 64 + lane];
      acc[ps * 4 + 0] += bf2f(u.x);
      acc[ps * 4 + 1] += bf2f(u.y);
      acc[ps * 4 + 2] += bf2f(u.z);
      acc[ps * 4 + 3] += bf2f(u.w);
    }
  }
  float rd = rdeg[id];
  ushort4* q = (ushort4*)(FB + (size_t)node * KREL + (size_t)(1 + rel) * DD);
#pragma unroll
  for (int ps = 0; ps < 3; ++ps) {
    ushort4 o;
    o.x = f2bf(acc[ps * 4 + 0] * rd);
    o.y = f2bf(acc[ps * 4 + 1] * rd);
    o.z = f2bf(acc[ps * 4 + 2] * rd);
    o.w = f2bf(acc[ps * 4 + 3] * rd);
    q[ps * 64 + lane] = o;
  }
}

// ---------------------------------------------------------------------------
// bf16 MFMA GEMM body: prefetched double-buffered LDS staging + vectorized
// epilogue (acc -> swizzled f32 LDS (reusing the 64KB staging buffer) ->
// row-major 16B vector global stores).
// smem = 32768 ushorts (64KB): As=smem (2x8192), Bs=smem+16384 (2x8192);
// epilogue reuses all 64KB as float[128][128] with col4^=(row&15) swizzle.
__device__ __forceinline__ void mgemm_body(
    const ushort* __restrict__ A, const ushort* __restrict__ BT,
    const float* __restrict__ bias, ushort* __restrict__ Cb,
    int M, int Kd, int Cstride, int relu, int bm, int bn, ushort* smem) {
  ushort* As = smem;
  ushort* Bs = smem + 16384;
  const int tid = threadIdx.x;
  const int wave = tid >> 6, lane = tid & 63;
  const int lrow = lane & 15, quad = lane >> 4;

  const ushort* gA[4];
  const ushort* gB[4];
#pragma unroll
  for (int j = 0; j < 4; ++j) {
    int c = (wave * 4 + j) * 64 + lane;
    int row = c >> 3, kslot = c & 7;
    int kb = kslot ^ (row & 7);
    int ar = bm + row; ar = ar < M ? ar : M - 1;
    gA[j] = A + (size_t)ar * Kd + kb * 8;
    gB[j] = BT + (size_t)(bn + row) * Kd + kb * 8;
  }

  f32x4 acc[4][4];
#pragma unroll
  for (int i = 0; i < 4; ++i)
#pragma unroll
    for (int j = 0; j < 4; ++j) acc[i][j] = (f32x4){0.f, 0.f, 0.f, 0.f};

  const int wm = (wave >> 1) * 64, wn = (wave & 1) * 64;
  const int KT = Kd >> 6;

  // prologue: stage kt=0 into half 0
#pragma unroll
  for (int j = 0; j < 4; ++j) {
    gload16(gA[j], &As[(wave * 4 + j) * 512]);
    gload16(gB[j], &Bs[(wave * 4 + j) * 512]);
    gA[j] += 64;
    gB[j] += 64;
  }
  __syncthreads();

  int cur = 0;
  for (int kt = 0; kt < KT; ++kt) {
    int nxt = cur ^ 1;
    if (kt + 1 < KT) {
#pragma unroll
      for (int j = 0; j < 4; ++j) {
        gload16(gA[j], &As[nxt * 8192 + (wave * 4 + j) * 512]);
        gload16(gB[j], &Bs[nxt * 8192 + (wave * 4 + j) * 512]);
        gA[j] += 64;
        gB[j] += 64;
      }
    }
    const ushort* Asc = As + cur * 8192;
    const ushort* Bsc = Bs + cur * 8192;
#pragma unroll
    for (int ks = 0; ks < 2; ++ks) {
      bf16x8 af[4], bfr[4];
#pragma unroll
      for (int mi = 0; mi < 4; ++mi) {
        int r = wm + mi * 16 + lrow;
        int kc = ks * 4 + quad;
        af[mi] = *(const bf16x8*)&Asc[r * 64 + ((kc ^ (r & 7)) * 8)];
      }
#pragma unroll
      for (int ni = 0; ni < 4; ++ni) {
        int r = wn + ni * 16 + lrow;
        int kc = ks * 4 + quad;
        bfr[ni] = *(const bf16x8*)&Bsc[r * 64 + ((kc ^ (r & 7)) * 8)];
      }
#pragma unroll
      for (int mi = 0; mi < 4; ++mi)
#pragma unroll
        for (int ni = 0; ni < 4; ++ni)
          acc[mi][ni] = __builtin_amdgcn_mfma_f32_16x16x32_bf16(
              af[mi], bfr[ni], acc[mi][ni], 0, 0, 0);
    }
    __syncthreads();
    cur = nxt;
  }

  // epilogue: acc -> LDS f32 (swizzled), then vectorized bias/relu store
  float* Cep = (float*)smem;
#pragma unroll
  for (int mi = 0; mi < 4; ++mi)
#pragma unroll
    for (int ni = 0; ni < 4; ++ni)
#pragma unroll
      for (int r = 0; r < 4; ++r) {
        int row = wm + mi * 16 + quad * 4 + r;
        int col = wn + ni * 16 + lrow;
        Cep[row * 128 + ((((col >> 2) ^ (row & 15)) << 2) | (col & 3))] =
            acc[mi][ni][r];
      }
  __syncthreads();
  {
    int r = tid >> 1, h = tid & 1;
    int grow = bm + r;
    if (grow < M) {
      int cbase = bn + h * 64;
      size_t base = (size_t)grow * Cstride + cbase;
#pragma unroll
      for (int g8 = 0; g8 < 8; ++g8) {
        int s0 = (h * 16 + g8 * 2) ^ (r & 15);
        int s1 = (h * 16 + g8 * 2 + 1) ^ (r & 15);
        float4 va = *(float4*)&Cep[r * 128 + s0 * 4];
        float4 vb = *(float4*)&Cep[r * 128 + s1 * 4];
        float vv[8] = {va.x, va.y, va.z, va.w, vb.x, vb.y, vb.z, vb.w};
        float bvv[8] = {0.f, 0.f, 0.f, 0.f, 0.f, 0.f, 0.f, 0.f};
        if (bias) {
          float4 ba = *(const float4*)&bias[cbase + g8 * 8];
          float4 bb = *(const float4*)&bias[cbase + g8 * 8 + 4];
          bvv[0] = ba.x; bvv[1] = ba.y; bvv[2] = ba.z; bvv[3] = ba.w;
          bvv[4] = bb.x; bvv[5] = bb.y; bvv[6] = bb.z; bvv[7] = bb.w;
        }
        u16x8 o;
#pragma unroll
        for (int e = 0; e < 8; ++e) {
          float t = vv[e] + bvv[e];
          if (relu) t = fmaxf(t, 0.f);
          o[e] = f2bf(t);
        }
        *(u16x8*)(Cb + base + g8 * 8) = o;
      }
    }
  }
}

__global__ __launch_bounds__(256) void k_mgemm(
    const ushort* __restrict__ A, const ushort* __restrict__ BT,
    const float* __restrict__ bias, ushort* __restrict__ Cb,
    int M, int Kd, int Cstride, int relu) {
  __shared__ __align__(16) ushort smem[32768];
  int2 b = xcd_swz(gridDim.x);
  mgemm_body(A, BT, bias, Cb, M, Kd, Cstride, relu, b.x * 128, b.y * 128, smem);
}

// fused Q,K projection: grid (12, 256); x<6 -> Q, x>=6 -> K
__global__ __launch_bounds__(256) void k_mgemm_qk(
    const ushort* __restrict__ A, const ushort* __restrict__ BTq,
    const ushort* __restrict__ BTk, const float* __restrict__ bq,
    const float* __restrict__ bk, ushort* __restrict__ Qb,
    ushort* __restrict__ Kb) {
  __shared__ __align__(16) ushort smem[32768];
  int2 b = xcd_swz(gridDim.x);
  int sel = b.y >= 6;
  mgemm_body(A, sel ? BTk : BTq, sel ? bk : bq, sel ? Kb : Qb, MSW, DD, DD, 0,
             b.x * 128, (b.y - sel * 6) * 128, smem);
}

// fused gated-GCN combine: G = [Od|Ol] @ [W1;W2] (K=1536); vectorized
// epilogue applies g = sigmoid(G + b1 + b2);
// dst = relu(g*Od + (1-g)*Ol + gb) [+ SE residual].
__global__ __launch_bounds__(256) void k_mgemm_gate(
    const ushort* __restrict__ Aod, const ushort* __restrict__ Aol,
    const ushort* __restrict__ BT, const float* __restrict__ b1,
    const float* __restrict__ b2, const float* __restrict__ gb,
    const float* __restrict__ SE, const int* __restrict__ gidx, int fuse_res,
    ushort* __restrict__ dst) {
  __shared__ __align__(16) ushort smem[32768];
  ushort* As = smem;
  ushort* Bs = smem + 16384;
  const int tid = threadIdx.x;
  const int wave = tid >> 6, lane = tid & 63;
  const int lrow = lane & 15, quad = lane >> 4;
  int2 bxy = xcd_swz(gridDim.x);
  const int bm = bxy.x * 128, bn = bxy.y * 128;

  size_t aoff[4], boff[4];
#pragma unroll
  for (int j = 0; j < 4; ++j) {
    int c = (wave * 4 + j) * 64 + lane;
    int row = c >> 3, kslot = c & 7;
    int kb = kslot ^ (row & 7);
    aoff[j] = (size_t)(bm + row) * DD + kb * 8;
    boff[j] = (size_t)(bn + row) * 1536 + kb * 8;
  }

  f32x4 acc[4][4];
#pragma unroll
  for (int i = 0; i < 4; ++i)
#pragma unroll
    for (int j = 0; j < 4; ++j) acc[i][j] = (f32x4){0.f, 0.f, 0.f, 0.f};

  const int wm = (wave >> 1) * 64, wn = (wave & 1) * 64;

  // prologue: stage kt=0 (A = Aod, ko = 0) into half 0
#pragma unroll
  for (int j = 0; j < 4; ++j) {
    gload16(Aod + aoff[j], &As[(wave * 4 + j) * 512]);
    gload16(BT + boff[j], &Bs[(wave * 4 + j) * 512]);
  }
  __syncthreads();

  int cur = 0;
  for (int kt = 0; kt < 24; ++kt) {
    int nxt = cur ^ 1;
    if (kt + 1 < 24) {
      int kn = kt + 1;
      const ushort* Abn = (kn < 12) ? Aod : Aol;
      const int kon = ((kn < 12) ? kn : kn - 12) << 6;
#pragma unroll
      for (int j = 0; j < 4; ++j) {
        gload16(Abn + aoff[j] + kon, &As[nxt * 8192 + (wave * 4 + j) * 512]);
        gload16(BT + boff[j] + (kn << 6), &Bs[nxt * 8192 + (wave * 4 + j) * 512]);
      }
    }
    const ushort* Asc = As + cur * 8192;
    const ushort* Bsc = Bs + cur * 8192;
#pragma unroll
    for (int ks = 0; ks < 2; ++ks) {
      bf16x8 af[4], bfr[4];
#pragma unroll
      for (int mi = 0; mi < 4; ++mi) {
        int r = wm + mi * 16 + lrow;
        int kc = ks * 4 + quad;
        af[mi] = *(const bf16x8*)&Asc[r * 64 + ((kc ^ (r & 7)) * 8)];
      }
#pragma unroll
      for (int ni = 0; ni < 4; ++ni) {
        int r = wn + ni * 16 + lrow;
        int kc = ks * 4 + quad;
        bfr[ni] = *(const bf16x8*)&Bsc[r * 64 + ((kc ^ (r & 7)) * 8)];
      }
#pragma unroll
      for (int mi = 0; mi < 4; ++mi)
#pragma unroll
        for (int ni = 0; ni < 4; ++ni)
          acc[mi][ni] = __builtin_amdgcn_mfma_f32_16x16x32_bf16(
              af[mi], bfr[ni], acc[mi][ni], 0, 0, 0);
    }
    __syncthreads();
    cur = nxt;
  }

  // epilogue: acc -> LDS f32 (swizzled) -> vectorized fused gate
  float* Cep = (float*)smem;
#pragma unroll
  for (int mi = 0; mi < 4; ++mi)
#pragma unroll
    for (int ni = 0; ni < 4; ++ni)
#pragma unroll
      for (int r = 0; r < 4; ++r) {
        int row = wm + mi * 16 + quad * 4 + r;
        int col = wn + ni * 16 + lrow;
        Cep[row * 128 + ((((col >> 2) ^ (row & 15)) << 2) | (col & 3))] =
            acc[mi][ni][r];
      }
  __syncthreads();
  {
    int r = tid >> 1, h = tid & 1;
    int grow = bm + r;
    int cbase = bn + h * 64;
    size_t base = (size_t)grow * DD + cbase;
    const float* sep = fuse_res ? (SE + (size_t)gidx[grow] * DD + cbase)
                                : (const float*)nullptr;
#pragma unroll
    for (int g8 = 0; g8 < 8; ++g8) {
      int s0 = (h * 16 + g8 * 2) ^ (r & 15);
      int s1 = (h * 16 + g8 * 2 + 1) ^ (r & 15);
      float4 va = *(float4*)&Cep[r * 128 + s0 * 4];
      float4 vb = *(float4*)&Cep[r * 128 + s1 * 4];
      float vv[8] = {va.x, va.y, va.z, va.w, vb.x, vb.y, vb.z, vb.w};
      float4 b1a = *(const float4*)&b1[cbase + g8 * 8];
      float4 b1b = *(const float4*)&b1[cbase + g8 * 8 + 4];
      float4 b2a = *(const float4*)&b2[cbase + g8 * 8];
      float4 b2b = *(const float4*)&b2[cbase + g8 * 8 + 4];
      float4 ga = *(const float4*)&gb[cbase + g8 * 8];
      float4 gbb = *(const float4*)&gb[cbase + g8 * 8 + 4];
      float bb[8] = {b1a.x + b2a.x, b1a.y + b2a.y, b1a.z + b2a.z,
                     b1a.w + b2a.w, b1b.x + b2b.x, b1b.y + b2b.y,
                     b1b.z + b2b.z, b1b.w + b2b.w};
      float gg[8] = {ga.x, ga.y, ga.z, ga.w, gbb.x, gbb.y, gbb.z, gbb.w};
      float sev[8] = {0.f, 0.f, 0.f, 0.f, 0.f, 0.f, 0.f, 0.f};
      if (fuse_res) {
        float4 sa = *(const float4*)&sep[g8 * 8];
        float4 sb = *(const float4*)&sep[g8 * 8 + 4];
        sev[0] = sa.x; sev[1] = sa.y; sev[2] = sa.z; sev[3] = sa.w;
        sev[4] = sb.x; sev[5] = sb.y; sev[6] = sb.z; sev[7] = sb.w;
      }
      u16x8 od8 = *(const u16x8*)(Aod + base + g8 * 8);
      u16x8 ol8 = *(const u16x8*)(Aol + base + g8 * 8);
      u16x8 o;
#pragma unroll
      for (int e = 0; e < 8; ++e) {
        float G = vv[e] + bb[e];
        float g = 1.f / (1.f + __expf(-G));
        float od = bf2f(od8[e]), ol = bf2f(ol8[e]);
        float t = fmaxf(g * od + (1.f - g) * ol + gg[e], 0.f) + sev[e];
        o[e] = f2bf(t);
      }
      *(u16x8*)(dst + base + g8 * 8) = o;
    }
  }
}

// ---------------------------------------------------------------------------
// Attention (MFMA QK^T) + exact entmax-1.5 in native MFMA fragment layout.
__device__ __forceinline__ void xlev4(float z[4], int j, bool ma, bool mb,
                                      bool mc, bool md) {
  float o0 = __shfl_xor(z[0], j, 16);
  float o1 = __shfl_xor(z[1], j, 16);
  float o2 = __shfl_xor(z[2], j, 16);
  float o3 = __shfl_xor(z[3], j, 16);
  z[0] = ma ? fmaxf(z[0], o0) : fminf(z[0], o0);
  z[1] = mb ? fmaxf(z[1], o1) : fminf(z[1], o1);
  z[2] = mc ? fmaxf(z[2], o2) : fminf(z[2], o2);
  z[3] = md ? fmaxf(z[3], o3) : fminf(z[3], o3);
}
__device__ __forceinline__ void rpair(float z[4], int a, int b, bool maxToA) {
  float hi = fmaxf(z[a], z[b]), lo = fminf(z[a], z[b]);
  z[a] = maxToA ? hi : lo;
  z[b] = maxToA ? lo : hi;
}

__global__ __launch_bounds__(256) void k_attn(const ushort* __restrict__ Q,
                                              const ushort* __restrict__ K,
                                              float* __restrict__ part) {
  __shared__ __align__(16) ushort ks[2][6144];
  const int s = blockIdx.x, hp = blockIdx.y;
  const int tid = threadIdx.x;
  const int wv = tid >> 6, lane = tid & 63;
  const int lrow = lane & 15, quad = lane >> 4;
  const int m0 = wv * 16;
  const float SC2 = 0.05103103630798288f;  // 0.5 / sqrt(96)
  const int h0 = hp * 2, h1 = hp * 2 + 1;

  const bool b1 = (lrow & 1) == 0, b2 = (lrow & 2) == 0,
             b4 = (lrow & 4) == 0, b8 = (lrow & 8) == 0;
  const bool s21 = b2 ? b1 : !b1;
  const bool s42 = b4 ? b2 : !b2, s41 = b4 ? b1 : !b1;
  const bool s84 = b8 ? b4 : !b4, s82 = b8 ? b2 : !b2, s81 = b8 ? b1 : !b1;

  float regacc[16];
#pragma unroll
  for (int i = 0; i < 16; ++i) regacc[i] = 0.f;

#pragma unroll
  for (int j = 0; j < 3; ++j) {
    int c = (j * 4 + wv) * 64 + lane;
    int row = c / 12, o = c - row * 12;
    gload16(K + (size_t)(s * 64 + row) * DD + h0 * 96 + o * 8,
            &ks[0][(j * 4 + wv) * 512]);
  }
  const ushort* qb0 = Q + (size_t)(s * 64 + m0 + lrow) * DD + h0 * 96 + quad * 8;
  bf16x8 qa0 = *(const bf16x8*)(qb0);
  bf16x8 qa1 = *(const bf16x8*)(qb0 + 32);
  bf16x8 qa2 = *(const bf16x8*)(qb0 + 64);
  __syncthreads();

#pragma unroll
  for (int hh = 0; hh < 2; ++hh) {
    f32x4 acc4[4];
#pragma unroll
    for (int t = 0; t < 4; ++t) acc4[t] = (f32x4){0.f, 0.f, 0.f, 0.f};
#pragma unroll
    for (int k = 0; k < 3; ++k) {
      bf16x8 a = (k == 0) ? qa0 : (k == 1) ? qa1 : qa2;
#pragma unroll
      for (int t = 0; t < 4; ++t) {
        bf16x8 b =
            *(const bf16x8*)&ks[hh][(t * 16 + lrow) * 96 + k * 32 + quad * 8];
        acc4[t] = __builtin_amdgcn_mfma_f32_16x16x32_bf16(a, b, acc4[t], 0, 0, 0);
      }
    }
    if (hh == 0) {
#pragma unroll
      for (int j = 0; j < 3; ++j) {
        int c = (j * 4 + wv) * 64 + lane;
        int row = c / 12, o = c - row * 12;
        gload16(K + (size_t)(s * 64 + row) * DD + h1 * 96 + o * 8,
                &ks[1][(j * 4 + wv) * 512]);
      }
      const ushort* qb1 =
          Q + (size_t)(s * 64 + m0 + lrow) * DD + h1 * 96 + quad * 8;
      qa0 = *(const bf16x8*)(qb1);
      qa1 = *(const bf16x8*)(qb1 + 32);
      qa2 = *(const bf16x8*)(qb1 + 64);
    }

#pragma unroll
    for (int r = 0; r < 4; ++r) {
      float z[4];
#pragma unroll
      for (int t = 0; t < 4; ++t) z[t] = acc4[t][r] * SC2;
      xlev4(z, 1, s21, s21, s21, s21);                      // k=2
      xlev4(z, 2, s42, s42, s42, s42);                      // k=4
      xlev4(z, 1, s41, s41, s41, s41);
      xlev4(z, 4, s84, s84, s84, s84);                      // k=8
      xlev4(z, 2, s82, s82, s82, s82);
      xlev4(z, 1, s81, s81, s81, s81);
      xlev4(z, 8, b8, !b8, b8, !b8);                        // k=16
      xlev4(z, 4, b4, !b4, b4, !b4);
      xlev4(z, 2, b2, !b2, b2, !b2);
      xlev4(z, 1, b1, !b1, b1, !b1);
      rpair(z, 0, 1, true); rpair(z, 2, 3, false);          // k=32, j=16
      xlev4(z, 8, b8, b8, !b8, !b8);
      xlev4(z, 4, b4, b4, !b4, !b4);
      xlev4(z, 2, b2, b2, !b2, !b2);
      xlev4(z, 1, b1, b1, !b1, !b1);
      rpair(z, 0, 2, true); rpair(z, 1, 3, true);           // k=64, j=32
      rpair(z, 0, 1, true); rpair(z, 2, 3, true);           // k=64, j=16
      xlev4(z, 8, b8, b8, b8, b8);
      xlev4(z, 4, b4, b4, b4, b4);
      xlev4(z, 2, b2, b2, b2, b2);
      xlev4(z, 1, b1, b1, b1, b1);

      float zmax = __shfl(z[0], 0, 16);
      float cz[4], czz[4];
#pragma unroll
      for (int t = 0; t < 4; ++t) {
        z[t] -= zmax;
        cz[t] = z[t];
        czz[t] = z[t] * z[t];
      }
#pragma unroll
      for (int off = 1; off < 16; off <<= 1) {
#pragma unroll
        for (int t = 0; t < 4; ++t) {
          float ta = __shfl_up(cz[t], off, 16);
          float tb = __shfl_up(czz[t], off, 16);
          if (lrow >= off) { cz[t] += ta; czz[t] += tb; }
        }
      }
      float accz = 0.f, acczz = 0.f;
      float tau[4];
      int cnt = 0;
#pragma unroll
      for (int t = 0; t < 4; ++t) {
        float tz = __shfl(cz[t], 15, 16);
        float tzz = __shfl(czz[t], 15, 16);
        cz[t] += accz; czz[t] += acczz;
        accz += tz; acczz += tzz;
        float kk = (float)(t * 16 + lrow + 1);
        float mean = cz[t] / kk;
        float ssv = kk * (czz[t] / kk - mean * mean);
        float delta = (1.f - ssv) / kk;
        float sq = delta > 0.f ? sqrtf(delta) : 0.f;
        tau[t] = mean - sq;
        cnt += (tau[t] <= z[t]) ? 1 : 0;
      }
#pragma unroll
      for (int off = 1; off < 16; off <<= 1) cnt += __shfl_xor(cnt, off, 16);
      int ts = (cnt - 1) >> 4, ls = (cnt - 1) & 15;
      float tt = ts == 0 ? tau[0] : ts == 1 ? tau[1] : ts == 2 ? tau[2] : tau[3];
      float tau_star = __shfl(tt, ls, 16);
#pragma unroll
      for (int t = 0; t < 4; ++t) {
        float p = fmaxf(acc4[t][r] * SC2 - zmax - tau_star, 0.f);
        regacc[r * 4 + t] += p * p;
      }
    }
    if (hh == 0) __syncthreads();
  }

#pragma unroll
  for (int r = 0; r < 4; ++r)
#pragma unroll
    for (int t = 0; t < 4; ++t)
      part[(size_t)hp * 2097152 +
           ((size_t)s * 64 + m0 + quad * 4 + r) * 64 + t * 16 + lrow] =
          regacc[r * 4 + t] * 0.125f;
}

// reduce 4 head-pair partials -> bf16 latent adjacency
__global__ __launch_bounds__(256) void k_latred(const float* __restrict__ part,
                                                ushort* __restrict__ latbf) {
  size_t i = (size_t)blockIdx.x * 256 + threadIdx.x;  // float4 units, 524288
  float4 a = ((const float4*)part)[i];
  float4 b = ((const float4*)(part + 2097152))[i];
  float4 c = ((const float4*)(part + 4194304))[i];
  float4 d = ((const float4*)(part + 6291456))[i];
  ushort4 o;
  o.x = f2bf(a.x + b.x + c.x + d.x);
  o.y = f2bf(a.y + b.y + c.y + d.y);
  o.z = f2bf(a.z + b.z + c.z + d.z);
  o.w = f2bf(a.w + b.w + c.w + d.w);
  ((ushort4*)latbf)[i] = o;
}

// ---------------------------------------------------------------------------
// Od[s]=dep[s]@Hh[s], Ol[s]=lat[s]@Hh[s]; 128-col tiles, grid (6, SS)
__global__ __launch_bounds__(256) void k_dualadj(const float* __restrict__ dep,
                                                 const ushort* __restrict__ lat,
                                                 const ushort* __restrict__ Hh,
                                                 ushort* __restrict__ Od,
                                                 ushort* __restrict__ Ol) {
  __shared__ float Pd[64][68];
  __shared__ ushort Pl[64][68];
  __shared__ float Hc[64][132];
  int2 bxy = xcd_swz(gridDim.x);
  const int s = bxy.x;
  const int c0 = bxy.y * 128;
  const int tid = threadIdx.x;
  const int tx = tid & 15, ty = tid >> 4;
  for (int i = tid; i < 4096; i += 256)
    Pd[i >> 6][i & 63] = dep[(size_t)s * 4096 + i];
  for (int i = tid; i < 1024; i += 256) {
    int r = i >> 4, c = (i & 15) * 4;
    ushort4 u = ((const ushort4*)(lat + (size_t)s * 4096))[i];
    Pl[r][c + 0] = u.x; Pl[r][c + 1] = u.y;
    Pl[r][c + 2] = u.z; Pl[r][c + 3] = u.w;
  }
  for (int i = tid; i < 2048; i += 256) {
    int r = i >> 5, c = (i & 31) * 4;
    ushort4 u = *(const ushort4*)(Hh + (size_t)(s * 64 + r) * DD + c0 + c);
    float4 f;
    f.x = bf2f(u.x); f.y = bf2f(u.y); f.z = bf2f(u.z); f.w = bf2f(u.w);
    *(float4*)&Hc[r][c] = f;
  }
  __syncthreads();
  float ad[4][8] = {}, al[4][8] = {};
  for (int w2 = 0; w2 < 64; ++w2) {
    float4 b0 = *(const float4*)&Hc[w2][tx * 4];
    float4 b1 = *(const float4*)&Hc[w2][64 + tx * 4];
    float bb[8] = {b0.x, b0.y, b0.z, b0.w, b1.x, b1.y, b1.z, b1.w};
    float pd[4], pl[4];
#pragma unroll
    for (int i = 0; i < 4; ++i) {
      pd[i] = Pd[ty * 4 + i][w2];
      pl[i] = bf2f(Pl[ty * 4 + i][w2]);
    }
#pragma unroll
    for (int i = 0; i < 4; ++i)
#pragma unroll
      for (int j = 0; j < 8; ++j) {
        ad[i][j] = fmaf(pd[i], bb[j], ad[i][j]);
        al[i][j] = fmaf(pl[i], bb[j], al[i][j]);
      }
  }
#pragma unroll
  for (int i = 0; i < 4; ++i) {
    size_t ro = (size_t)(s * 64 + ty * 4 + i) * DD + c0;
    ushort4 v;
#pragma unroll
    for (int hh = 0; hh < 2; ++hh) {
      v.x = f2bf(ad[i][hh * 4 + 0]); v.y = f2bf(ad[i][hh * 4 + 1]);
      v.z = f2bf(ad[i][hh * 4 + 2]); v.w = f2bf(ad[i][hh * 4 + 3]);
      *(ushort4*)&Od[ro + hh * 64 + tx * 4] = v;
      v.x = f2bf(al[i][hh * 4 + 0]); v.y = f2bf(al[i][hh * 4 + 1]);
      v.z = f2bf(al[i][hh * 4 + 2]); v.w = f2bf(al[i][hh * 4 + 3]);
      *(ushort4*)&Ol[ro + hh * 64 + tx * 4] = v;
    }
  }
}

// node feature assembly -> bf16 FBIG[NN, KREL] (cols 0:768)
__global__ __launch_bounds__(256) void k_feats(const float* __restrict__ doc,
                                               const float* __restrict__ scls,
                                               const int* __restrict__ t_sid,
                                               const int* __restrict__ t_index,
                                               const ushort* __restrict__ X,
                                               ushort* __restrict__ F) {
  size_t i = (size_t)blockIdx.x * 256 + threadIdx.x;
  if (i >= (size_t)NN * 192) return;
  size_t n = i / 192, q = i % 192;
  ushort4 o;
  if (n <= SS) {
    float4 v = (n == 0) ? ((const float4*)doc)[q]
                        : ((const float4*)scls)[(n - 1) * 192 + q];
    o.x = f2bf(v.x); o.y = f2bf(v.y); o.z = f2bf(v.z); o.w = f2bf(v.w);
  } else {
    size_t t = n - 1 - SS;
    size_t row = (size_t)t_sid[t] * WW + t_index[t];
    o = ((const ushort4*)X)[row * 192 + q];
  }
  ((ushort4*)(F + n * KREL))[q] = o;
}

// final predictor; F/h1 strided (FBIG col 0), h2 contiguous
__global__ __launch_bounds__(256) void k_pred(const ushort* __restrict__ F,
                                              const ushort* __restrict__ h1,
                                              const ushort* __restrict__ h2,
                                              const float* __restrict__ pw,
                                              const float* __restrict__ pb,
                                              float* __restrict__ out) {
  const int n = blockIdx.x;
  const int tid = threadIdx.x;
  float acc[5] = {};
  for (int k = tid; k < 3 * DD; k += 256) {
    float v;
    if (k < DD) v = bf2f(F[(size_t)n * KREL + k]);
    else if (k < 2 * DD) v = bf2f(h1[(size_t)n * KREL + k - DD]);
    else v = bf2f(h2[(size_t)n * DD + k - 2 * DD]);
    const float* w = pw + (size_t)k * 5;
#pragma unroll
    for (int o = 0; o < 5; ++o) acc[o] = fmaf(v, w[o], acc[o]);
  }
#pragma unroll
  for (int o = 0; o < 5; ++o)
    for (int off = 32; off; off >>= 1) acc[o] += __shfl_xor(acc[o], off, 64);
  __shared__ float red[5][4];
  const int wv = tid >> 6, lane = tid & 63;
  if (lane == 0)
#pragma unroll
    for (int o = 0; o < 5; ++o) red[o][wv] = acc[o];
  __syncthreads();
  if (tid == 0)
#pragma unroll
    for (int o = 0; o < 5; ++o)
      out[(size_t)n * 5 + o] = red[o][0] + red[o][1] + red[o][2] + red[o][3] + pb[o];
}

// ---------------------------------------------------------------------------
extern "C" void kernel_launch(void* const* d_in, const int* in_sizes, int n_in,
                              void* d_out, int out_size, void* d_ws, size_t ws_size,
                              hipStream_t stream) {
  const float* sent_embed = (const float*)d_in[0];
  const float* s_idx      = (const float*)d_in[1];
  const float* dep_adj    = (const float*)d_in[2];
  const float* doc_cls    = (const float*)d_in[3];
  const float* sent_cls   = (const float*)d_in[4];
  const int*   t_sid      = (const int*)d_in[5];
  const int*   t_index    = (const int*)d_in[6];
  const int*   e_src      = (const int*)d_in[7];
  const int*   e_dst      = (const int*)d_in[8];
  const float* wq_b = (const float*)d_in[10];
  const float* wk_b = (const float*)d_in[12];
  const float* gc1_b   = (const float*)d_in[14];
  const float* gc1_l1b = (const float*)d_in[16];
  const float* gc1_l2b = (const float*)d_in[18];
  const float* gc2_b   = (const float*)d_in[20];
  const float* gc2_l1b = (const float*)d_in[22];
  const float* gc2_l2b = (const float*)d_in[24];
  const float* rel1_b = (const float*)d_in[27];
  const float* rel2_b = (const float*)d_in[30];
  const float* pred_w = (const float*)d_in[31];
  const float* pred_b = (const float*)d_in[32];
  float* out = (float*)d_out;

  // workspace carve (byte offsets), ~264 MiB total
  char* W = (char*)d_ws;
  ushort* A0 = (ushort*)W;                          // 64 MiB: WEbf -> FBIG2
  ushort* A1 = (ushort*)(W + (64ll << 20));         // 64 MiB: Q/Hh -> FBIG1
  ushort* A2 = (ushort*)(W + (128ll << 20));        // 48 MiB: K/Od
  ushort* A3 = (ushort*)(W + (176ll << 20));        // 48 MiB: PART/Ol
  ushort* LATbf = (ushort*)(W + (224ll << 20));     // 4 MiB
  ushort* WBF = (ushort*)(W + (228ll << 20));       // 10 MiB (4 sq + 2 concat)
  ushort* WR  = (ushort*)(W + (238ll << 20));       // 11.25 MiB (2x768x3840)
  ushort* H2  = (ushort*)(W + (250ll << 20));       // 12.75 MiB
  char* M0 = W + (263ll << 20);
  int*   GIDX = (int*)M0;                           // 131072 B
  int*   DEGC = (int*)(M0 + 140000);
  float* RDEG = (float*)(M0 + 280000);
  int*   OFFS = (int*)(M0 + 420000);                // (NPAIR+1)*4
  int*   CUR  = (int*)(M0 + 560000);
  int*   ELIST= (int*)(M0 + 700000);                // 131072 B

  ushort* WEbf = A0;
  ushort* Qbf = A1, *Kbf = A2;
  float*  PART = (float*)A3;
  ushort* Hh = A1, *Od = A2, *Ol = A3;
  ushort* FBIG1 = A1;
  ushort* FBIG2 = A0;
  const size_t WRSZ = (size_t)DD * KREL;  // 2949120
  // gate weights: [768][1536] concat (l1w^T | l2w^T)
  ushort* WG1 = WBF + 4 * (size_t)WSZ;
  ushort* WG2 = WG1 + (size_t)DD * 1536;

  WTJobs wj;
  wj.j[0] = {(const float*)d_in[9],  WBF + 0 * (size_t)WSZ, DD};   // wq
  wj.j[1] = {(const float*)d_in[11], WBF + 1 * (size_t)WSZ, DD};   // wk
  wj.j[2] = {(const float*)d_in[13], WBF + 2 * (size_t)WSZ, DD};   // gc1_w
  wj.j[3] = {(const float*)d_in[15], WG1, 1536};                   // gc1_l1w
  wj.j[4] = {(const float*)d_in[17], WG1 + 768, 1536};             // gc1_l2w
  wj.j[5] = {(const float*)d_in[19], WBF + 3 * (size_t)WSZ, DD};   // gc2_w
  wj.j[6] = {(const float*)d_in[21], WG2, 1536};                   // gc2_l1w
  wj.j[7] = {(const float*)d_in[23], WG2 + 768, 1536};             // gc2_l2w
  wj.j[8] = {(const float*)d_in[26], WR + 0 * WRSZ, KREL};         // rel1 loop
  for (int r = 0; r < 4; ++r)
    wj.j[9 + r] = {(const float*)d_in[25] + (size_t)r * WSZ,
                   WR + 0 * WRSZ + (size_t)(1 + r) * DD, KREL};
  wj.j[13] = {(const float*)d_in[29], WR + 1 * WRSZ, KREL};        // rel2 loop
  for (int r = 0; r < 4; ++r)
    wj.j[14 + r] = {(const float*)d_in[28] + (size_t)r * WSZ,
                    WR + 1 * WRSZ + (size_t)(1 + r) * DD, KREL};

  dim3 blk(256);

  // 0) prep
  k_wtall<<<18 * 576, blk, 0, stream>>>(wj);
  k_pos<<<MSW / 4, blk, 0, stream>>>(s_idx, GIDX);
  k_gather<<<24576, blk, 0, stream>>>(sent_embed, GIDX, WEbf);
  hipMemsetAsync(DEGC, 0, NPAIR * 4, stream);
  hipMemsetAsync(CUR, 0, NPAIR * 4, stream);
  k_deg4<<<4 * EG / 256, blk, 0, stream>>>(e_dst, DEGC);
  k_rcp<<<(NPAIR + 255) / 256, blk, 0, stream>>>(DEGC, RDEG);
  k_scan<<<1, 1024, 0, stream>>>(DEGC, OFFS);
  k_fill<<<4 * EG / 256, blk, 0, stream>>>(e_src, e_dst, OFFS, CUR, ELIST);

  // 1) Q,K projections + attention + reduce
  k_mgemm_qk<<<dim3(12, 256), blk, 0, stream>>>(WEbf, WBF + 0 * (size_t)WSZ,
                                                WBF + 1 * (size_t)WSZ, wq_b, wk_b,
                                                Qbf, Kbf);
  k_attn<<<dim3(SS, 4), blk, 0, stream>>>(Qbf, Kbf, PART);
  k_latred<<<2048, blk, 0, stream>>>(PART, LATbf);

  // 2) gated GCN layers (fused gate-GEMM: K=1536 over [Od|Ol], vec epilogue)
  const float* l1b[2] = {gc1_l1b, gc2_l1b};
  const float* l2b[2] = {gc1_l2b, gc2_l2b};
  const float* gb[2] = {gc1_b, gc2_b};
  for (int l = 0; l < 2; ++l) {
    k_mgemm<<<dim3(6, 256), blk, 0, stream>>>(WEbf,
        WBF + (size_t)(2 + l) * WSZ, nullptr, Hh, MSW, DD, DD, 0);
    k_dualadj<<<dim3(6, SS), blk, 0, stream>>>(dep_adj, LATbf, Hh, Od, Ol);
    k_mgemm_gate<<<dim3(6, 256), blk, 0, stream>>>(
        Od, Ol, l == 0 ? WG1 : WG2, l1b[l], l2b[l], gb[l], sent_embed, GIDX,
        l == 1 ? 1 : 0, WEbf);
  }

  // 3) node features into FBIG1 col 0
  k_feats<<<6529, blk, 0, stream>>>(doc_cls, sent_cls, t_sid, t_index, WEbf, FBIG1);

  // 4) two relational GCN layers: CSR gather + one fused K=3840 GEMM each
  k_preagg<<<(NPAIR + 3) / 4, blk, 0, stream>>>(FBIG1, OFFS, ELIST, RDEG);
  k_mgemm<<<dim3(6, 69), blk, 0, stream>>>(FBIG1, WR + 0 * WRSZ, rel1_b,
                                           FBIG2, NN, KREL, KREL, 1);
  k_preagg<<<(NPAIR + 3) / 4, blk, 0, stream>>>(FBIG2, OFFS, ELIST, RDEG);
  k_mgemm<<<dim3(6, 69), blk, 0, stream>>>(FBIG2, WR + 1 * WRSZ, rel2_b,
                                           H2, NN, KREL, DD, 1);

  // 5) predictor
  k_pred<<<NN, blk, 0, stream>>>(FBIG1, FBIG2, H2, pred_w, pred_b, out);
}